// Round 16
// baseline (1032.764 us; speedup 1.0000x reference)
//
#include <hip/hip_runtime.h>
#include <cstddef>

#define BATCH 32
#define NPTS  1024
#define K_NN  12
#define HID   64
#define BN_EPS 1e-5f

typedef short bf16x8 __attribute__((ext_vector_type(8)));
typedef float f32x4 __attribute__((ext_vector_type(4)));

// ---------------------------------------------------------------------------
// d2[j] = ||x_j||^2 (layer-0 input only; later layers fused into egapply).
// ---------------------------------------------------------------------------
template<int C>
__global__ __launch_bounds__(256) void d2_kernel(const float* __restrict__ x,
                                                 float* __restrict__ d2) {
  int gid = blockIdx.x * 256 + threadIdx.x;          // < B*N
  const float* xp = x + (size_t)gid * C;
  float s = 0.f;
#pragma unroll
  for (int c = 0; c < C; ++c) { float v = xp[c]; s = fmaf(v, v, s); }
  d2[gid] = s;
}

// ---------------------------------------------------------------------------
// split of layer-0's output is fused into egapply; this standalone version
// is no longer needed (kept out). Split math (shared with egapply):
// x = h + m + l, bf16 RNE each, Sterbenz-exact residuals (24 mantissa bits).
// ---------------------------------------------------------------------------

// ---------------------------------------------------------------------------
// kNN C=64 MFMA part (v16). 256 thr = 4 waves; grid.z = 4 j-quadrants ->
// 2048 blocks (R15 was 512 = 2 blocks/CU; 88 VGPR caps 512-thr blocks at 2).
// Wave scans 64 j in 16-j chunks: 16x16 dot tiles via 6-product split-bf16
// v_mfma_f32_16x16x32_bf16, D -> per-wave LDS slab [64][17], lane=i row scan
// + exact (d,j) lexicographic insert. In-block merge of 4 wave-lists; the
// 4 quadrant lists merge in knn_merge_kernel (ascending z = ascending j:
// stability preserved, R10-proven).
// ---------------------------------------------------------------------------
__global__ __launch_bounds__(256, 4) void knn64_mfma_part_kernel(
    const unsigned short* __restrict__ xh, const unsigned short* __restrict__ xm,
    const unsigned short* __restrict__ xl, const float* __restrict__ d2,
    float* __restrict__ cand_d, int* __restrict__ cand_j) {
  const int b    = blockIdx.y;
  const int z    = blockIdx.z;                       // j-quadrant 0..3
  const int lane = threadIdx.x & 63;
  const int wv_u = __builtin_amdgcn_readfirstlane(threadIdx.x >> 6);  // 0..3
  const int i0   = blockIdx.x * 64;
  const size_t bbase = (size_t)b * NPTS;
  const float* d2b = d2 + bbase;

  constexpr int NE = 4 * K_NN;                       // 48 merge entries/row
  __shared__ __align__(16) char smem[64 * (NE + 1) * 8];   // 25088 B
  float* slab  = (float*)(smem + wv_u * (64 * 17 * 4));    // 4 x 4352 B
  float* lds_d = (float*)smem;                       // [64][49] (after sync)
  int*   lds_j = (int*)(smem + 64 * (NE + 1) * 4);

  const int qr = lane >> 4;                          // quad 0..3
  const int lr = lane & 15;

  float bd[K_NN]; int bj[K_NN];
#pragma unroll
  for (int k = 0; k < K_NN; ++k) { bd[k] = 3.4e38f; bj[k] = 0x7fffffff; }

  const int j0 = z * 256 + wv_u * 64;                // uniform slice base
#pragma unroll 1
  for (int chunk = 0; chunk < 4; ++chunk) {
    const int jb = j0 + chunk * 16;
    // B frags: n = lr -> point jb+lr ; k = qr*8 + e
    const size_t brow = (bbase + jb + lr) * HID;
    bf16x8 Bh0 = *(const bf16x8*)(xh + brow + 0  + qr * 8);
    bf16x8 Bh1 = *(const bf16x8*)(xh + brow + 32 + qr * 8);
    bf16x8 Bm0 = *(const bf16x8*)(xm + brow + 0  + qr * 8);
    bf16x8 Bm1 = *(const bf16x8*)(xm + brow + 32 + qr * 8);
    bf16x8 Bl0 = *(const bf16x8*)(xl + brow + 0  + qr * 8);
    bf16x8 Bl1 = *(const bf16x8*)(xl + brow + 32 + qr * 8);

    f32x4 acc[4];
#pragma unroll
    for (int isub = 0; isub < 4; ++isub) acc[isub] = f32x4{0.f, 0.f, 0.f, 0.f};

#pragma unroll
    for (int isub = 0; isub < 4; ++isub) {
      const size_t arow = (bbase + i0 + isub * 16 + lr) * HID;
      bf16x8 Ah0 = *(const bf16x8*)(xh + arow + 0  + qr * 8);
      bf16x8 Ah1 = *(const bf16x8*)(xh + arow + 32 + qr * 8);
      bf16x8 Am0 = *(const bf16x8*)(xm + arow + 0  + qr * 8);
      bf16x8 Am1 = *(const bf16x8*)(xm + arow + 32 + qr * 8);
      bf16x8 Al0 = *(const bf16x8*)(xl + arow + 0  + qr * 8);
      bf16x8 Al1 = *(const bf16x8*)(xl + arow + 32 + qr * 8);
      f32x4 a = acc[isub];
      a = __builtin_amdgcn_mfma_f32_16x16x32_bf16(Ah0, Bh0, a, 0, 0, 0);
      a = __builtin_amdgcn_mfma_f32_16x16x32_bf16(Ah1, Bh1, a, 0, 0, 0);
      a = __builtin_amdgcn_mfma_f32_16x16x32_bf16(Ah0, Bm0, a, 0, 0, 0);
      a = __builtin_amdgcn_mfma_f32_16x16x32_bf16(Ah1, Bm1, a, 0, 0, 0);
      a = __builtin_amdgcn_mfma_f32_16x16x32_bf16(Am0, Bh0, a, 0, 0, 0);
      a = __builtin_amdgcn_mfma_f32_16x16x32_bf16(Am1, Bh1, a, 0, 0, 0);
      a = __builtin_amdgcn_mfma_f32_16x16x32_bf16(Ah0, Bl0, a, 0, 0, 0);
      a = __builtin_amdgcn_mfma_f32_16x16x32_bf16(Ah1, Bl1, a, 0, 0, 0);
      a = __builtin_amdgcn_mfma_f32_16x16x32_bf16(Al0, Bh0, a, 0, 0, 0);
      a = __builtin_amdgcn_mfma_f32_16x16x32_bf16(Al1, Bh1, a, 0, 0, 0);
      a = __builtin_amdgcn_mfma_f32_16x16x32_bf16(Am0, Bm0, a, 0, 0, 0);
      a = __builtin_amdgcn_mfma_f32_16x16x32_bf16(Am1, Bm1, a, 0, 0, 0);
      acc[isub] = a;
    }

    // D -> slab: row = isub*16 + qr*4 + r, col = lr
#pragma unroll
    for (int isub = 0; isub < 4; ++isub)
#pragma unroll
      for (int r = 0; r < 4; ++r)
        slab[(isub * 16 + qr * 4 + r) * 17 + lr] = acc[isub][r];

    // lane = i-row, scan 16 j's ascending (stable order)
#pragma unroll 4
    for (int jj = 0; jj < 16; ++jj) {
      const int j = jb + jj;                         // uniform
      const float dot = slab[lane * 17 + jj];
      // d2_i (row-constant) dropped: doesn't change per-row top-k order.
      const float dval = fmaf(-2.f, dot, d2b[j]);    // uniform s_load
      if (dval < bd[K_NN - 1]) {                     // strict <: lower j wins
        float dk = dval; int jk = j;
#pragma unroll
        for (int s = 0; s < K_NN; ++s) {             // exact branchless insert
          bool sw = dk < bd[s];
          float nd = fminf(dk, bd[s]);
          float xd = fmaxf(dk, bd[s]);
          int nj = sw ? jk : bj[s];
          int xjj = sw ? bj[s] : jk;
          bd[s] = nd; bj[s] = nj; dk = xd; jk = xjj;
        }
      }
    }
  }

  __syncthreads();                                   // slabs dead -> merge arrays
#pragma unroll
  for (int k = 0; k < K_NN; ++k) {
    lds_d[lane * (NE + 1) + wv_u * K_NN + k] = bd[k];
    lds_j[lane * (NE + 1) + wv_u * K_NN + k] = bj[k];
  }
  __syncthreads();

  if (wv_u == 0) {                                   // merge 4 wave slices
    float md[K_NN]; int mj[K_NN];
#pragma unroll
    for (int k = 0; k < K_NN; ++k) { md[k] = 3.4e38f; mj[k] = 0x7fffffff; }
    for (int e = 0; e < NE; ++e) {                   // ascending wave order
      float dk = lds_d[lane * (NE + 1) + e];
      int jk = lds_j[lane * (NE + 1) + e];
      if (dk < md[K_NN - 1]) {
#pragma unroll
        for (int s = 0; s < K_NN; ++s) {
          bool sw = dk < md[s];
          float nd = fminf(dk, md[s]);
          float xd = fmaxf(dk, md[s]);
          int nj = sw ? jk : mj[s];
          int xjj = sw ? mj[s] : jk;
          md[s] = nd; mj[s] = nj; dk = xd; jk = xjj;
        }
      }
    }
    const size_t row = bbase + i0 + lane;
    float* cd = cand_d + (row * 4 + z) * K_NN;
    int*   cj = cand_j + (row * 4 + z) * K_NN;
#pragma unroll
    for (int k = 0; k < K_NN; ++k) { cd[k] = md[k]; cj[k] = mj[k]; }
  }
}

// ---------------------------------------------------------------------------
// knn merge: 4 quadrant lists of 12 -> final 12 (ascending z = ascending j;
// strict < keeps lower j on ties = jax.lax.top_k). R10-proven.
// ---------------------------------------------------------------------------
__global__ __launch_bounds__(256) void knn_merge_kernel(
    const float* __restrict__ cand_d, const int* __restrict__ cand_j,
    int* __restrict__ idx) {
  const int row = blockIdx.x * 256 + threadIdx.x;    // 0..32767
  const float* cd = cand_d + (size_t)row * (4 * K_NN);
  const int*   cj = cand_j + (size_t)row * (4 * K_NN);
  float md[K_NN]; int mj[K_NN];
#pragma unroll
  for (int k = 0; k < K_NN; ++k) { md[k] = 3.4e38f; mj[k] = 0x7fffffff; }
#pragma unroll 4
  for (int e = 0; e < 4 * K_NN; ++e) {
    float dk = cd[e]; int jk = cj[e];
    if (dk < md[K_NN - 1]) {
#pragma unroll
      for (int s = 0; s < K_NN; ++s) {
        bool sw = dk < md[s];
        float nd = fminf(dk, md[s]);
        float xd = fmaxf(dk, md[s]);
        int nj = sw ? jk : mj[s];
        int xjj = sw ? mj[s] : jk;
        md[s] = nd; mj[s] = nj; dk = xd; jk = xjj;
      }
    }
  }
  int* op = idx + (size_t)row * K_NN;
#pragma unroll
  for (int k = 0; k < K_NN; ++k) op[k] = mj[k];
}

// ---------------------------------------------------------------------------
// kNN C=3 (layer 0): xi[3] in registers, scalar v_fma with SGPR xj.
// ---------------------------------------------------------------------------
__global__ __launch_bounds__(512, 2) void knn3_kernel(
    const float* __restrict__ x, const float* __restrict__ d2,
    int* __restrict__ idx) {
  const int b    = blockIdx.y;
  const int lane = threadIdx.x & 63;
  const int wv_u = __builtin_amdgcn_readfirstlane(threadIdx.x >> 6);  // 0..7
  const int i    = blockIdx.x * 64 + lane;
  const float* xb  = x  + (size_t)b * NPTS * 3;
  const float* d2b = d2 + (size_t)b * NPTS;

  constexpr int NE = 8 * K_NN;
  __shared__ float lds_d[64][NE + 1];
  __shared__ int   lds_j[64][NE + 1];

  float xi0 = xb[(size_t)i * 3 + 0];
  float xi1 = xb[(size_t)i * 3 + 1];
  float xi2v = xb[(size_t)i * 3 + 2];

  float bd[K_NN]; int bj[K_NN];
#pragma unroll
  for (int k = 0; k < K_NN; ++k) { bd[k] = 3.4e38f; bj[k] = 0x7fffffff; }

  const int j0 = wv_u * 128;
#pragma unroll 2
  for (int jj = 0; jj < 128; ++jj) {
    const int j = j0 + jj;                           // uniform
    const float* xj = xb + (size_t)j * 3;            // uniform -> s_load
    const float d2j = d2b[j];
    float dot = fmaf(xi0, xj[0], 0.f);
    dot = fmaf(xi1, xj[1], dot);
    dot = fmaf(xi2v, xj[2], dot);
    const float dval = fmaf(-2.f, dot, d2j);
    if (dval < bd[K_NN - 1]) {
      float dk = dval; int jk = j;
#pragma unroll
      for (int s = 0; s < K_NN; ++s) {
        bool sw = dk < bd[s];
        float nd = fminf(dk, bd[s]);
        float xd = fmaxf(dk, bd[s]);
        int nj = sw ? jk : bj[s];
        int xjj = sw ? bj[s] : jk;
        bd[s] = nd; bj[s] = nj; dk = xd; jk = xjj;
      }
    }
  }

#pragma unroll
  for (int k = 0; k < K_NN; ++k) {
    lds_d[lane][wv_u * K_NN + k] = bd[k];
    lds_j[lane][wv_u * K_NN + k] = bj[k];
  }
  __syncthreads();

  if (wv_u == 0) {
    float md[K_NN]; int mj[K_NN];
#pragma unroll
    for (int k = 0; k < K_NN; ++k) { md[k] = 3.4e38f; mj[k] = 0x7fffffff; }
    for (int e = 0; e < NE; ++e) {
      float dk = lds_d[lane][e]; int jk = lds_j[lane][e];
      if (dk < md[K_NN - 1]) {
#pragma unroll
        for (int s = 0; s < K_NN; ++s) {
          bool sw = dk < md[s];
          float nd = fminf(dk, md[s]);
          float xd = fmaxf(dk, md[s]);
          int nj = sw ? jk : mj[s];
          int xjj = sw ? mj[s] : jk;
          md[s] = nd; mj[s] = nj; dk = xd; jk = xjj;
        }
      }
    }
    int* op = idx + ((size_t)b * NPTS + blockIdx.x * 64 + lane) * K_NN;
#pragma unroll
    for (int k = 0; k < K_NN; ++k) op[k] = mj[k];
  }
}

// ---------------------------------------------------------------------------
// rowgemm2: dual-output 64x64 rowgemm, W1a-W1b folded into LDS staging.
// ---------------------------------------------------------------------------
__global__ __launch_bounds__(256) void rowgemm2_kernel(
    const float* __restrict__ X, const float* __restrict__ waL,
    const float* __restrict__ biasA,
    float* __restrict__ YA, float* __restrict__ YB) {
  __shared__ float wsa[HID * HID];
  __shared__ float wsb[HID * HID];
  for (int t = threadIdx.x; t < HID * HID; t += 256) {
    float wbv = waL[4096 + t];
    wsa[t] = waL[t] - wbv;
    wsb[t] = wbv;
  }
  __syncthreads();

  const int lane = threadIdx.x & 63;
  const int wv   = threadIdx.x >> 6;
  const int fq   = lane & 15;
  const int rg   = lane >> 4;
  const int r0   = blockIdx.x * 32 + wv * 8 + rg * 2;

  const float4* X4 = (const float4*)X;
  const float4* WA4 = (const float4*)wsa;
  const float4* WB4 = (const float4*)wsb;
  float aA0[4] = {0,0,0,0}, aA1[4] = {0,0,0,0};
  float aB0[4] = {0,0,0,0}, aB1[4] = {0,0,0,0};

#pragma unroll 2
  for (int cq = 0; cq < 16; ++cq) {
    float4 xa = X4[(size_t)r0 * 16 + cq];
    float4 xb_ = X4[(size_t)(r0 + 1) * 16 + cq];
    float ea[4] = {xa.x, xa.y, xa.z, xa.w};
    float eb[4] = {xb_.x, xb_.y, xb_.z, xb_.w};
#pragma unroll
    for (int d = 0; d < 4; ++d) {
      float4 wa4 = WA4[(cq * 4 + d) * 16 + fq];
      float4 wb4 = WB4[(cq * 4 + d) * 16 + fq];
      float wA[4] = {wa4.x, wa4.y, wa4.z, wa4.w};
      float wB[4] = {wb4.x, wb4.y, wb4.z, wb4.w};
#pragma unroll
      for (int k = 0; k < 4; ++k) {
        aA0[k] = fmaf(ea[d], wA[k], aA0[k]);
        aA1[k] = fmaf(eb[d], wA[k], aA1[k]);
        aB0[k] = fmaf(ea[d], wB[k], aB0[k]);
        aB1[k] = fmaf(eb[d], wB[k], aB1[k]);
      }
    }
  }
  float4 b4 = ((const float4*)biasA)[fq];
  float4 oA0{aA0[0] + b4.x, aA0[1] + b4.y, aA0[2] + b4.z, aA0[3] + b4.w};
  float4 oA1{aA1[0] + b4.x, aA1[1] + b4.y, aA1[2] + b4.z, aA1[3] + b4.w};
  float4 oB0{aB0[0], aB0[1], aB0[2], aB0[3]};
  float4 oB1{aB1[0], aB1[1], aB1[2], aB1[3]};
  ((float4*)YA)[(size_t)r0 * 16 + fq] = oA0;
  ((float4*)YA)[(size_t)(r0 + 1) * 16 + fq] = oA1;
  ((float4*)YB)[(size_t)r0 * 16 + fq] = oB0;
  ((float4*)YB)[(size_t)(r0 + 1) * 16 + fq] = oB1;
}

// ---------------------------------------------------------------------------
// dual3: layer-0 projections (C=3), subtraction folded into staging.
// ---------------------------------------------------------------------------
__global__ __launch_bounds__(256) void dual3_kernel(
    const float* __restrict__ x, const float* __restrict__ w0a,
    const float* __restrict__ b1,
    float* __restrict__ hxi, float* __restrict__ hxj) {
  __shared__ float Cs[3 * HID], Bs[3 * HID], bs[HID];
  for (int t = threadIdx.x; t < 3 * HID; t += 256) {
    float bv = w0a[192 + t];
    Cs[t] = w0a[t] - bv;
    Bs[t] = bv;
  }
  if (threadIdx.x < HID) bs[threadIdx.x] = b1[threadIdx.x];
  __syncthreads();

  const int lane = threadIdx.x & 63;
  const int wv   = __builtin_amdgcn_readfirstlane(threadIdx.x >> 6);
  const int node0 = blockIdx.x * 32;
#pragma unroll 1
  for (int it = 0; it < 8; ++it) {
    const int n = node0 + it * 4 + wv;               // uniform
    const float* xr = x + (size_t)n * 3;             // uniform -> s_load
    float x0 = xr[0], x1 = xr[1], x2 = xr[2];
    float hi = bs[lane];
    hi = fmaf(x0, Cs[0 * HID + lane], hi);
    hi = fmaf(x1, Cs[1 * HID + lane], hi);
    hi = fmaf(x2, Cs[2 * HID + lane], hi);
    float hj = x0 * Bs[0 * HID + lane];
    hj = fmaf(x1, Bs[1 * HID + lane], hj);
    hj = fmaf(x2, Bs[2 * HID + lane], hj);
    hxi[(size_t)n * HID + lane] = hi;
    hxj[(size_t)n * HID + lane] = hj;
  }
}

// ---------------------------------------------------------------------------
// egstats: BN sum/sumsq over all edges of h = hxi[n] + hxj[j].
// ---------------------------------------------------------------------------
__global__ __launch_bounds__(256) void egstats_kernel(
    const int* __restrict__ idx, const float* __restrict__ hxi,
    const float* __restrict__ hxj, float* __restrict__ partial) {
  const int lane = threadIdx.x & 63;
  const int wv   = __builtin_amdgcn_readfirstlane(threadIdx.x >> 6);
  const int node0 = blockIdx.x * 32;
  float s1 = 0.f, s2 = 0.f;

#pragma unroll 1
  for (int it = 0; it < 4; ++it) {
    const int n0 = node0 + it * 8 + wv;              // uniform
    const int n1 = n0 + 4;
    const int bbase = (n0 >> 10) << 10;
    const int* ip0 = idx + (size_t)n0 * K_NN;        // uniform -> s_load
    const int* ip1 = idx + (size_t)n1 * K_NN;
    int j0[K_NN], j1[K_NN];
#pragma unroll
    for (int k = 0; k < K_NN; ++k) { j0[k] = ip0[k]; j1[k] = ip1[k]; }
    const float hv0 = hxi[(size_t)n0 * HID + lane];
    const float hv1 = hxi[(size_t)n1 * HID + lane];
    float v0[K_NN], v1[K_NN];
#pragma unroll
    for (int k = 0; k < K_NN; ++k) {
      v0[k] = hxj[(size_t)(bbase + j0[k]) * HID + lane];
      v1[k] = hxj[(size_t)(bbase + j1[k]) * HID + lane];
    }
#pragma unroll
    for (int k = 0; k < K_NN; ++k) {
      float h0 = hv0 + v0[k], h1 = hv1 + v1[k];
      s1 += h0 + h1;
      s2 = fmaf(h0, h0, s2); s2 = fmaf(h1, h1, s2);
    }
  }

  __shared__ float red[4][HID];
  red[wv][lane] = s1;
  __syncthreads();
  if (threadIdx.x < HID)
    partial[(size_t)blockIdx.x * 128 + lane] =
        (red[0][lane] + red[1][lane]) + (red[2][lane] + red[3][lane]);
  __syncthreads();
  red[wv][lane] = s2;
  __syncthreads();
  if (threadIdx.x < HID)
    partial[(size_t)blockIdx.x * 128 + 64 + lane] =
        (red[0][lane] + red[1][lane]) + (red[2][lane] + red[3][lane]);
}

// ---------------------------------------------------------------------------
__global__ void bn_reduce_finalize_kernel(const float* __restrict__ g,
                                          const float* __restrict__ be,
                                          const float* __restrict__ partial,
                                          float* __restrict__ stats) {
  int t = threadIdx.x;                               // 0..127
  float a0 = 0.f, a1 = 0.f, a2 = 0.f, a3 = 0.f;
  for (int gb = 0; gb < 1024; gb += 4) {
    a0 += partial[(size_t)(gb + 0) * 128 + t];
    a1 += partial[(size_t)(gb + 1) * 128 + t];
    a2 += partial[(size_t)(gb + 2) * 128 + t];
    a3 += partial[(size_t)(gb + 3) * 128 + t];
  }
  __shared__ float sm[128];
  sm[t] = (a0 + a1) + (a2 + a3);
  __syncthreads();
  if (t < HID) {
    const float inv_n = 1.f / (float)(BATCH * NPTS * K_NN);
    float m = sm[t] * inv_n;
    float v = sm[HID + t] * inv_n - m * m;
    float A = g[t] * rsqrtf(v + BN_EPS);
    stats[128 + t] = A;
    stats[192 + t] = be[t] - m * A;
  }
}

// ---------------------------------------------------------------------------
// egapply_gemm: BN-apply + relu + mean-over-K + W2 + b2 + fused d2 of the
// output row + fused bf16 3-way split of the output (feeds next knn; kills
// the standalone split kernel).
// ---------------------------------------------------------------------------
__global__ __launch_bounds__(256) void egapply_gemm_kernel(
    const int* __restrict__ idx, const float* __restrict__ hxi,
    const float* __restrict__ hxj, const float* __restrict__ stats,
    const float* __restrict__ W2, const float* __restrict__ b2,
    float* __restrict__ out, float* __restrict__ d2out,
    unsigned short* __restrict__ xsh, unsigned short* __restrict__ xsm,
    unsigned short* __restrict__ xsl) {
  __shared__ float w2s[HID * HID];
  __shared__ float red[32][HID];
  for (int t = threadIdx.x; t < HID * HID; t += 256) w2s[t] = W2[t];

  const int lane = threadIdx.x & 63;
  const int wv   = __builtin_amdgcn_readfirstlane(threadIdx.x >> 6);
  const int node0 = blockIdx.x * 32;
  const float A = stats[128 + lane], Bc = stats[192 + lane];

#pragma unroll 1
  for (int it = 0; it < 4; ++it) {
    const int n0 = node0 + it * 8 + wv;              // uniform
    const int n1 = n0 + 4;
    const int bbase = (n0 >> 10) << 10;
    const int* ip0 = idx + (size_t)n0 * K_NN;        // uniform -> s_load
    const int* ip1 = idx + (size_t)n1 * K_NN;
    int j0[K_NN], j1[K_NN];
#pragma unroll
    for (int k = 0; k < K_NN; ++k) { j0[k] = ip0[k]; j1[k] = ip1[k]; }
    const float hv0 = hxi[(size_t)n0 * HID + lane];
    const float hv1 = hxi[(size_t)n1 * HID + lane];
    float v0[K_NN], v1[K_NN];
#pragma unroll
    for (int k = 0; k < K_NN; ++k) {
      v0[k] = hxj[(size_t)(bbase + j0[k]) * HID + lane];
      v1[k] = hxj[(size_t)(bbase + j1[k]) * HID + lane];
    }
    float a0 = 0.f, a1 = 0.f;
#pragma unroll
    for (int k = 0; k < K_NN; ++k) {
      a0 += fmaxf(fmaf(A, hv0 + v0[k], Bc), 0.f);
      a1 += fmaxf(fmaf(A, hv1 + v1[k], Bc), 0.f);
    }
    red[it * 8 + wv][lane] = a0;
    red[it * 8 + 4 + wv][lane] = a1;
  }
  __syncthreads();

  const float b2f = b2[lane];
  const float inv = 1.f / (float)K_NN;
#pragma unroll 2
  for (int p = 0; p < 8; ++p) {
    int rr = p * 4 + wv;                             // uniform row
    float acc = 0.f;
#pragma unroll 8
    for (int h = 0; h < HID; ++h) acc = fmaf(red[rr][h], w2s[h * HID + lane], acc);
    float val = fmaf(acc, inv, b2f);
    const size_t o = (size_t)(node0 + rr) * HID + lane;
    out[o] = val;

    // bf16 3-way split (RNE, Sterbenz-exact residuals)
    unsigned u = __float_as_uint(val);
    unsigned short hh = (unsigned short)((u + 0x7FFFu + ((u >> 16) & 1u)) >> 16);
    float r1 = val - __uint_as_float((unsigned)hh << 16);
    unsigned ur = __float_as_uint(r1);
    unsigned short mm = (unsigned short)((ur + 0x7FFFu + ((ur >> 16) & 1u)) >> 16);
    float r2 = r1 - __uint_as_float((unsigned)mm << 16);
    unsigned ur2 = __float_as_uint(r2);
    unsigned short ll = (unsigned short)((ur2 + 0x7FFFu + ((ur2 >> 16) & 1u)) >> 16);
    xsh[o] = hh; xsm[o] = mm; xsl[o] = ll;

    float sq = val * val;                            // fused d2 of the row
#pragma unroll
    for (int off = 1; off < 64; off <<= 1) sq += __shfl_xor(sq, off, 64);
    if (lane == 0) d2out[node0 + rr] = sq;
  }
}

// ---------------------------------------------------------------------------
__global__ __launch_bounds__(256) void pool_kernel(const float* __restrict__ h,
                                                   float* __restrict__ pooled) {
  const int b = blockIdx.x;
  const int f = threadIdx.x & 63;
  const int gsz = threadIdx.x >> 6;
  __shared__ float red[4][HID];
  float s = 0.f;
  for (int n = gsz; n < NPTS; n += 4) s += h[((size_t)b * NPTS + n) * HID + f];
  red[gsz][f] = s;
  __syncthreads();
  if (threadIdx.x < HID)
    pooled[b * HID + f] = ((red[0][f] + red[1][f]) + (red[2][f] + red[3][f])) * (1.f / (float)NPTS);
}

__global__ __launch_bounds__(256) void head_kernel(const float* __restrict__ pooled,
    const float* __restrict__ wf1, const float* __restrict__ bf1,
    const float* __restrict__ gf, const float* __restrict__ bef,
    const float* __restrict__ wf2, const float* __restrict__ bf2,
    float* __restrict__ out) {
  __shared__ float pl[BATCH * HID];
  __shared__ float t[BATCH * 32];
  __shared__ float Ab[32], Bb[32];
  for (int i = threadIdx.x; i < BATCH * HID; i += 256) pl[i] = pooled[i];
  __syncthreads();
  for (int i = threadIdx.x; i < BATCH * 32; i += 256) {
    int s = i >> 5, f1 = i & 31;
    float acc = bf1[f1];
    for (int h = 0; h < HID; ++h) acc = fmaf(pl[s * HID + h], wf1[h * 32 + f1], acc);
    t[i] = acc;
  }
  __syncthreads();
  if (threadIdx.x < 32) {
    int f1 = threadIdx.x;
    float m = 0.f;
    for (int s = 0; s < BATCH; ++s) m += t[s * 32 + f1];
    m *= (1.f / (float)BATCH);
    float v = 0.f;
    for (int s = 0; s < BATCH; ++s) { float d = t[s * 32 + f1] - m; v = fmaf(d, d, v); }
    v *= (1.f / (float)BATCH);
    float A = gf[f1] * rsqrtf(v + BN_EPS);
    Ab[f1] = A; Bb[f1] = bef[f1] - m * A;
  }
  __syncthreads();
  for (int i = threadIdx.x; i < BATCH * 32; i += 256) {
    int f1 = i & 31;
    t[i] = fmaxf(fmaf(Ab[f1], t[i], Bb[f1]), 0.f);
  }
  __syncthreads();
  if (threadIdx.x < BATCH * 2) {
    int s = threadIdx.x >> 1, o = threadIdx.x & 1;
    float acc = bf2[o];
    for (int f1 = 0; f1 < 32; ++f1) acc = fmaf(t[s * 32 + f1], wf2[f1 * 2 + o], acc);
    out[s * 2 + o] = acc;
  }
}

// ---------------------------------------------------------------------------
extern "C" void kernel_launch(void* const* d_in, const int* in_sizes, int n_in,
                              void* d_out, int out_size, void* d_ws, size_t ws_size,
                              hipStream_t stream) {
  const float* x   = (const float*)d_in[0];
  const float* w0a = (const float*)d_in[1];
  const float* b0a = (const float*)d_in[2];
  const float* g0  = (const float*)d_in[3];
  const float* be0 = (const float*)d_in[4];
  const float* w0b = (const float*)d_in[5];
  const float* b0b = (const float*)d_in[6];
  const float* wa  = (const float*)d_in[7];
  const float* ba  = (const float*)d_in[8];
  const float* ga  = (const float*)d_in[9];
  const float* bea = (const float*)d_in[10];
  const float* wb  = (const float*)d_in[11];
  const float* bb  = (const float*)d_in[12];
  const float* wf1 = (const float*)d_in[13];
  const float* bf1 = (const float*)d_in[14];
  const float* gf  = (const float*)d_in[15];
  const float* bef = (const float*)d_in[16];
  const float* wf2 = (const float*)d_in[17];
  const float* bf2 = (const float*)d_in[18];

  float* ws = (float*)d_ws;
  const size_t HN = (size_t)BATCH * NPTS * HID;         // 2,097,152
  const size_t ROWS = (size_t)BATCH * NPTS;             // 32768
  float* bufA    = ws;                                  // HN
  float* bufB    = bufA + HN;                           // HN
  float* hxi     = bufB + HN;                           // HN
  float* hxjb    = hxi + HN;                            // HN
  int*   idxb    = (int*)(hxjb + HN);                   // ROWS*12
  float* d2buf   = (float*)(idxb + ROWS * K_NN);        // ROWS
  float* stats   = d2buf + ROWS;                        // 256
  float* partial = stats + 256;                         // 1024*128
  float* pooled  = partial + 1024 * 128;                // 2048
  unsigned short* xsh = (unsigned short*)(pooled + 2048);   // HN bf16
  unsigned short* xsm = xsh + HN;
  unsigned short* xsl = xsm + HN;
  // cand buffers alias hxi/hxjb: knn_part+merge run BEFORE rowgemm2
  // overwrites the region (stream-ordered). 32768*48 <= HN.
  float* cand_d  = hxi;
  int*   cand_j  = (int*)hxjb;
  // total ~46 MB of workspace

  // ---- layer 0 (C=3, gather path) ----
  d2_kernel<3><<<(int)(ROWS / 256), 256, 0, stream>>>(x, d2buf);
  knn3_kernel<<<dim3(16, BATCH), 512, 0, stream>>>(x, d2buf, idxb);
  dual3_kernel<<<1024, 256, 0, stream>>>(x, w0a, b0a, hxi, hxjb);
  egstats_kernel<<<1024, 256, 0, stream>>>(idxb, hxi, hxjb, partial);
  bn_reduce_finalize_kernel<<<1, 128, 0, stream>>>(g0, be0, partial, stats);
  egapply_gemm_kernel<<<1024, 256, 0, stream>>>(idxb, hxi, hxjb, stats, w0b, b0b,
                                                bufA, d2buf, xsh, xsm, xsl);

  // ---- layers 1..3 (MFMA knn + gather path) ----
  const float* cur = bufA;
  float* nxt = bufB;
  for (int i = 0; i < 3; ++i) {
    knn64_mfma_part_kernel<<<dim3(16, BATCH, 4), 256, 0, stream>>>(
        xsh, xsm, xsl, d2buf, cand_d, cand_j);
    knn_merge_kernel<<<128, 256, 0, stream>>>(cand_d, cand_j, idxb);
    rowgemm2_kernel<<<(int)(ROWS / 32), 256, 0, stream>>>(cur, wa + (size_t)i * 8192,
                                                          ba + i * HID, hxi, hxjb);
    egstats_kernel<<<1024, 256, 0, stream>>>(idxb, hxi, hxjb, partial);
    bn_reduce_finalize_kernel<<<1, 128, 0, stream>>>(ga + i * HID, bea + i * HID, partial, stats);
    egapply_gemm_kernel<<<1024, 256, 0, stream>>>(idxb, hxi, hxjb, stats,
                                                  wb + (size_t)i * 4096, bb + i * HID,
                                                  nxt, d2buf, xsh, xsm, xsl);
    const float* t = cur; cur = nxt; nxt = (float*)t;
  }

  pool_kernel<<<BATCH, 256, 0, stream>>>(cur, pooled);
  head_kernel<<<1, 256, 0, stream>>>(pooled, wf1, bf1, gf, bef, wf2, bf2, (float*)d_out);
}

// Round 17
// 923.457 us; speedup vs baseline: 1.1184x; 1.1184x over previous
//
#include <hip/hip_runtime.h>
#include <cstddef>

#define BATCH 32
#define NPTS  1024
#define K_NN  12
#define HID   64
#define BN_EPS 1e-5f

typedef short bf16x8 __attribute__((ext_vector_type(8)));
typedef float f32x4 __attribute__((ext_vector_type(4)));

// ---------------------------------------------------------------------------
// d2[j] = ||x_j||^2 (layer-0 input only; later layers fused into egapply).
// ---------------------------------------------------------------------------
template<int C>
__global__ __launch_bounds__(256) void d2_kernel(const float* __restrict__ x,
                                                 float* __restrict__ d2) {
  int gid = blockIdx.x * 256 + threadIdx.x;          // < B*N
  const float* xp = x + (size_t)gid * C;
  float s = 0.f;
#pragma unroll
  for (int c = 0; c < C; ++c) { float v = xp[c]; s = fmaf(v, v, s); }
  d2[gid] = s;
}

// ---------------------------------------------------------------------------
// kNN C=64 via MFMA — R15's proven body (143 us, no spills; R16's 256-thr
// 4-quadrant reshape spilled: WRITE 103 MB, FETCH 215 MB — reverted).
// Block = 64 i x 8 waves; wave scans its 128-j slice in 16-j chunks.
// Per chunk: 16x16 dot tiles via 6-product split-bf16 mfma_f32_16x16x32_bf16
// (split is numerically transparent: absmax unchanged at 0.00195 in R15),
// D -> per-wave LDS slab [64][17], lane=i row scan + exact (d,j)
// lexicographic insert (ascending j, strict < = jax.lax.top_k order).
// ---------------------------------------------------------------------------
__global__ __launch_bounds__(512, 2) void knn64_mfma_kernel(
    const unsigned short* __restrict__ xh, const unsigned short* __restrict__ xm,
    const unsigned short* __restrict__ xl, const float* __restrict__ d2,
    int* __restrict__ idx) {
  const int b    = blockIdx.y;
  const int lane = threadIdx.x & 63;
  const int wv_u = __builtin_amdgcn_readfirstlane(threadIdx.x >> 6);  // 0..7
  const int i0   = blockIdx.x * 64;
  const size_t bbase = (size_t)b * NPTS;
  const float* d2b = d2 + bbase;

  constexpr int NE = 8 * K_NN;                       // 96
  __shared__ __align__(16) char smem[64 * (NE + 1) * 8];   // 49664 B
  float* slab  = (float*)(smem + wv_u * (64 * 17 * 4));    // 8 x 4352 B
  float* lds_d = (float*)smem;                       // merge arrays (after sync)
  int*   lds_j = (int*)(smem + 64 * (NE + 1) * 4);

  const int qr = lane >> 4;                          // quad 0..3
  const int lr = lane & 15;

  float bd[K_NN]; int bj[K_NN];
#pragma unroll
  for (int k = 0; k < K_NN; ++k) { bd[k] = 3.4e38f; bj[k] = 0x7fffffff; }

  const int j0 = wv_u * 128;
#pragma unroll 1
  for (int chunk = 0; chunk < 8; ++chunk) {
    const int jb = j0 + chunk * 16;
    // B frags: n = lr -> point jb+lr ; k = qr*8 + e
    const size_t brow = (bbase + jb + lr) * HID;
    bf16x8 Bh0 = *(const bf16x8*)(xh + brow + 0  + qr * 8);
    bf16x8 Bh1 = *(const bf16x8*)(xh + brow + 32 + qr * 8);
    bf16x8 Bm0 = *(const bf16x8*)(xm + brow + 0  + qr * 8);
    bf16x8 Bm1 = *(const bf16x8*)(xm + brow + 32 + qr * 8);
    bf16x8 Bl0 = *(const bf16x8*)(xl + brow + 0  + qr * 8);
    bf16x8 Bl1 = *(const bf16x8*)(xl + brow + 32 + qr * 8);

    f32x4 acc[4];
#pragma unroll
    for (int isub = 0; isub < 4; ++isub) acc[isub] = f32x4{0.f, 0.f, 0.f, 0.f};

#pragma unroll
    for (int isub = 0; isub < 4; ++isub) {
      const size_t arow = (bbase + i0 + isub * 16 + lr) * HID;
      bf16x8 Ah0 = *(const bf16x8*)(xh + arow + 0  + qr * 8);
      bf16x8 Ah1 = *(const bf16x8*)(xh + arow + 32 + qr * 8);
      bf16x8 Am0 = *(const bf16x8*)(xm + arow + 0  + qr * 8);
      bf16x8 Am1 = *(const bf16x8*)(xm + arow + 32 + qr * 8);
      bf16x8 Al0 = *(const bf16x8*)(xl + arow + 0  + qr * 8);
      bf16x8 Al1 = *(const bf16x8*)(xl + arow + 32 + qr * 8);
      f32x4 a = acc[isub];
      a = __builtin_amdgcn_mfma_f32_16x16x32_bf16(Ah0, Bh0, a, 0, 0, 0);
      a = __builtin_amdgcn_mfma_f32_16x16x32_bf16(Ah1, Bh1, a, 0, 0, 0);
      a = __builtin_amdgcn_mfma_f32_16x16x32_bf16(Ah0, Bm0, a, 0, 0, 0);
      a = __builtin_amdgcn_mfma_f32_16x16x32_bf16(Ah1, Bm1, a, 0, 0, 0);
      a = __builtin_amdgcn_mfma_f32_16x16x32_bf16(Am0, Bh0, a, 0, 0, 0);
      a = __builtin_amdgcn_mfma_f32_16x16x32_bf16(Am1, Bh1, a, 0, 0, 0);
      a = __builtin_amdgcn_mfma_f32_16x16x32_bf16(Ah0, Bl0, a, 0, 0, 0);
      a = __builtin_amdgcn_mfma_f32_16x16x32_bf16(Ah1, Bl1, a, 0, 0, 0);
      a = __builtin_amdgcn_mfma_f32_16x16x32_bf16(Al0, Bh0, a, 0, 0, 0);
      a = __builtin_amdgcn_mfma_f32_16x16x32_bf16(Al1, Bh1, a, 0, 0, 0);
      a = __builtin_amdgcn_mfma_f32_16x16x32_bf16(Am0, Bm0, a, 0, 0, 0);
      a = __builtin_amdgcn_mfma_f32_16x16x32_bf16(Am1, Bm1, a, 0, 0, 0);
      acc[isub] = a;
    }

    // D -> slab: row = isub*16 + qr*4 + r, col = lr (stride 17)
#pragma unroll
    for (int isub = 0; isub < 4; ++isub)
#pragma unroll
      for (int r = 0; r < 4; ++r)
        slab[(isub * 16 + qr * 4 + r) * 17 + lr] = acc[isub][r];

    // lane = i-row, scan 16 j's ascending (stable order)
#pragma unroll 4
    for (int jj = 0; jj < 16; ++jj) {
      const int j = jb + jj;                         // uniform
      const float dot = slab[lane * 17 + jj];
      // d2_i (row-constant) dropped: doesn't change per-row top-k order.
      const float dval = fmaf(-2.f, dot, d2b[j]);    // uniform s_load
      if (dval < bd[K_NN - 1]) {                     // strict <: lower j wins
        float dk = dval; int jk = j;
#pragma unroll
        for (int s = 0; s < K_NN; ++s) {             // exact branchless insert
          bool sw = dk < bd[s];
          float nd = fminf(dk, bd[s]);
          float xd = fmaxf(dk, bd[s]);
          int nj = sw ? jk : bj[s];
          int xjj = sw ? bj[s] : jk;
          bd[s] = nd; bj[s] = nj; dk = xd; jk = xjj;
        }
      }
    }
  }

  __syncthreads();                                   // slabs dead -> merge arrays
#pragma unroll
  for (int k = 0; k < K_NN; ++k) {
    lds_d[lane * (NE + 1) + wv_u * K_NN + k] = bd[k];
    lds_j[lane * (NE + 1) + wv_u * K_NN + k] = bj[k];
  }
  __syncthreads();

  if (wv_u == 0) {                                   // merge 8 sorted slices
    float md[K_NN]; int mj[K_NN];
#pragma unroll
    for (int k = 0; k < K_NN; ++k) { md[k] = 3.4e38f; mj[k] = 0x7fffffff; }
    for (int e = 0; e < NE; ++e) {                   // ascending slice order
      float dk = lds_d[lane * (NE + 1) + e];
      int jk = lds_j[lane * (NE + 1) + e];
      if (dk < md[K_NN - 1]) {
#pragma unroll
        for (int s = 0; s < K_NN; ++s) {
          bool sw = dk < md[s];
          float nd = fminf(dk, md[s]);
          float xd = fmaxf(dk, md[s]);
          int nj = sw ? jk : mj[s];
          int xjj = sw ? mj[s] : jk;
          md[s] = nd; mj[s] = nj; dk = xd; jk = xjj;
        }
      }
    }
    int* op = idx + ((size_t)b * NPTS + i0 + lane) * K_NN;
#pragma unroll
    for (int k = 0; k < K_NN; ++k) op[k] = mj[k];
  }
}

// ---------------------------------------------------------------------------
// kNN C=3 (layer 0): xi[3] in registers, scalar v_fma with SGPR xj.
// ---------------------------------------------------------------------------
__global__ __launch_bounds__(512, 2) void knn3_kernel(
    const float* __restrict__ x, const float* __restrict__ d2,
    int* __restrict__ idx) {
  const int b    = blockIdx.y;
  const int lane = threadIdx.x & 63;
  const int wv_u = __builtin_amdgcn_readfirstlane(threadIdx.x >> 6);  // 0..7
  const int i    = blockIdx.x * 64 + lane;
  const float* xb  = x  + (size_t)b * NPTS * 3;
  const float* d2b = d2 + (size_t)b * NPTS;

  constexpr int NE = 8 * K_NN;
  __shared__ float lds_d[64][NE + 1];
  __shared__ int   lds_j[64][NE + 1];

  float xi0 = xb[(size_t)i * 3 + 0];
  float xi1 = xb[(size_t)i * 3 + 1];
  float xi2v = xb[(size_t)i * 3 + 2];

  float bd[K_NN]; int bj[K_NN];
#pragma unroll
  for (int k = 0; k < K_NN; ++k) { bd[k] = 3.4e38f; bj[k] = 0x7fffffff; }

  const int j0 = wv_u * 128;
#pragma unroll 2
  for (int jj = 0; jj < 128; ++jj) {
    const int j = j0 + jj;                           // uniform
    const float* xj = xb + (size_t)j * 3;            // uniform -> s_load
    const float d2j = d2b[j];
    float dot = fmaf(xi0, xj[0], 0.f);
    dot = fmaf(xi1, xj[1], dot);
    dot = fmaf(xi2v, xj[2], dot);
    const float dval = fmaf(-2.f, dot, d2j);
    if (dval < bd[K_NN - 1]) {
      float dk = dval; int jk = j;
#pragma unroll
      for (int s = 0; s < K_NN; ++s) {
        bool sw = dk < bd[s];
        float nd = fminf(dk, bd[s]);
        float xd = fmaxf(dk, bd[s]);
        int nj = sw ? jk : bj[s];
        int xjj = sw ? bj[s] : jk;
        bd[s] = nd; bj[s] = nj; dk = xd; jk = xjj;
      }
    }
  }

#pragma unroll
  for (int k = 0; k < K_NN; ++k) {
    lds_d[lane][wv_u * K_NN + k] = bd[k];
    lds_j[lane][wv_u * K_NN + k] = bj[k];
  }
  __syncthreads();

  if (wv_u == 0) {
    float md[K_NN]; int mj[K_NN];
#pragma unroll
    for (int k = 0; k < K_NN; ++k) { md[k] = 3.4e38f; mj[k] = 0x7fffffff; }
    for (int e = 0; e < NE; ++e) {
      float dk = lds_d[lane][e]; int jk = lds_j[lane][e];
      if (dk < md[K_NN - 1]) {
#pragma unroll
        for (int s = 0; s < K_NN; ++s) {
          bool sw = dk < md[s];
          float nd = fminf(dk, md[s]);
          float xd = fmaxf(dk, md[s]);
          int nj = sw ? jk : mj[s];
          int xjj = sw ? mj[s] : jk;
          md[s] = nd; mj[s] = nj; dk = xd; jk = xjj;
        }
      }
    }
    int* op = idx + ((size_t)b * NPTS + blockIdx.x * 64 + lane) * K_NN;
#pragma unroll
    for (int k = 0; k < K_NN; ++k) op[k] = mj[k];
  }
}

// ---------------------------------------------------------------------------
// rowgemm2: dual-output 64x64 rowgemm, W1a-W1b folded into LDS staging.
// ---------------------------------------------------------------------------
__global__ __launch_bounds__(256) void rowgemm2_kernel(
    const float* __restrict__ X, const float* __restrict__ waL,
    const float* __restrict__ biasA,
    float* __restrict__ YA, float* __restrict__ YB) {
  __shared__ float wsa[HID * HID];
  __shared__ float wsb[HID * HID];
  for (int t = threadIdx.x; t < HID * HID; t += 256) {
    float wbv = waL[4096 + t];
    wsa[t] = waL[t] - wbv;
    wsb[t] = wbv;
  }
  __syncthreads();

  const int lane = threadIdx.x & 63;
  const int wv   = threadIdx.x >> 6;
  const int fq   = lane & 15;
  const int rg   = lane >> 4;
  const int r0   = blockIdx.x * 32 + wv * 8 + rg * 2;

  const float4* X4 = (const float4*)X;
  const float4* WA4 = (const float4*)wsa;
  const float4* WB4 = (const float4*)wsb;
  float aA0[4] = {0,0,0,0}, aA1[4] = {0,0,0,0};
  float aB0[4] = {0,0,0,0}, aB1[4] = {0,0,0,0};

#pragma unroll 2
  for (int cq = 0; cq < 16; ++cq) {
    float4 xa = X4[(size_t)r0 * 16 + cq];
    float4 xb_ = X4[(size_t)(r0 + 1) * 16 + cq];
    float ea[4] = {xa.x, xa.y, xa.z, xa.w};
    float eb[4] = {xb_.x, xb_.y, xb_.z, xb_.w};
#pragma unroll
    for (int d = 0; d < 4; ++d) {
      float4 wa4 = WA4[(cq * 4 + d) * 16 + fq];
      float4 wb4 = WB4[(cq * 4 + d) * 16 + fq];
      float wA[4] = {wa4.x, wa4.y, wa4.z, wa4.w};
      float wB[4] = {wb4.x, wb4.y, wb4.z, wb4.w};
#pragma unroll
      for (int k = 0; k < 4; ++k) {
        aA0[k] = fmaf(ea[d], wA[k], aA0[k]);
        aA1[k] = fmaf(eb[d], wA[k], aA1[k]);
        aB0[k] = fmaf(ea[d], wB[k], aB0[k]);
        aB1[k] = fmaf(eb[d], wB[k], aB1[k]);
      }
    }
  }
  float4 b4 = ((const float4*)biasA)[fq];
  float4 oA0{aA0[0] + b4.x, aA0[1] + b4.y, aA0[2] + b4.z, aA0[3] + b4.w};
  float4 oA1{aA1[0] + b4.x, aA1[1] + b4.y, aA1[2] + b4.z, aA1[3] + b4.w};
  float4 oB0{aB0[0], aB0[1], aB0[2], aB0[3]};
  float4 oB1{aB1[0], aB1[1], aB1[2], aB1[3]};
  ((float4*)YA)[(size_t)r0 * 16 + fq] = oA0;
  ((float4*)YA)[(size_t)(r0 + 1) * 16 + fq] = oA1;
  ((float4*)YB)[(size_t)r0 * 16 + fq] = oB0;
  ((float4*)YB)[(size_t)(r0 + 1) * 16 + fq] = oB1;
}

// ---------------------------------------------------------------------------
// dual3: layer-0 projections (C=3), subtraction folded into staging.
// ---------------------------------------------------------------------------
__global__ __launch_bounds__(256) void dual3_kernel(
    const float* __restrict__ x, const float* __restrict__ w0a,
    const float* __restrict__ b1,
    float* __restrict__ hxi, float* __restrict__ hxj) {
  __shared__ float Cs[3 * HID], Bs[3 * HID], bs[HID];
  for (int t = threadIdx.x; t < 3 * HID; t += 256) {
    float bv = w0a[192 + t];
    Cs[t] = w0a[t] - bv;
    Bs[t] = bv;
  }
  if (threadIdx.x < HID) bs[threadIdx.x] = b1[threadIdx.x];
  __syncthreads();

  const int lane = threadIdx.x & 63;
  const int wv   = __builtin_amdgcn_readfirstlane(threadIdx.x >> 6);
  const int node0 = blockIdx.x * 32;
#pragma unroll 1
  for (int it = 0; it < 8; ++it) {
    const int n = node0 + it * 4 + wv;               // uniform
    const float* xr = x + (size_t)n * 3;             // uniform -> s_load
    float x0 = xr[0], x1 = xr[1], x2 = xr[2];
    float hi = bs[lane];
    hi = fmaf(x0, Cs[0 * HID + lane], hi);
    hi = fmaf(x1, Cs[1 * HID + lane], hi);
    hi = fmaf(x2, Cs[2 * HID + lane], hi);
    float hj = x0 * Bs[0 * HID + lane];
    hj = fmaf(x1, Bs[1 * HID + lane], hj);
    hj = fmaf(x2, Bs[2 * HID + lane], hj);
    hxi[(size_t)n * HID + lane] = hi;
    hxj[(size_t)n * HID + lane] = hj;
  }
}

// ---------------------------------------------------------------------------
// egstats: BN sum/sumsq over all edges of h = hxi[n] + hxj[j].
// ---------------------------------------------------------------------------
__global__ __launch_bounds__(256) void egstats_kernel(
    const int* __restrict__ idx, const float* __restrict__ hxi,
    const float* __restrict__ hxj, float* __restrict__ partial) {
  const int lane = threadIdx.x & 63;
  const int wv   = __builtin_amdgcn_readfirstlane(threadIdx.x >> 6);
  const int node0 = blockIdx.x * 32;
  float s1 = 0.f, s2 = 0.f;

#pragma unroll 1
  for (int it = 0; it < 4; ++it) {
    const int n0 = node0 + it * 8 + wv;              // uniform
    const int n1 = n0 + 4;
    const int bbase = (n0 >> 10) << 10;
    const int* ip0 = idx + (size_t)n0 * K_NN;        // uniform -> s_load
    const int* ip1 = idx + (size_t)n1 * K_NN;
    int j0[K_NN], j1[K_NN];
#pragma unroll
    for (int k = 0; k < K_NN; ++k) { j0[k] = ip0[k]; j1[k] = ip1[k]; }
    const float hv0 = hxi[(size_t)n0 * HID + lane];
    const float hv1 = hxi[(size_t)n1 * HID + lane];
    float v0[K_NN], v1[K_NN];
#pragma unroll
    for (int k = 0; k < K_NN; ++k) {
      v0[k] = hxj[(size_t)(bbase + j0[k]) * HID + lane];
      v1[k] = hxj[(size_t)(bbase + j1[k]) * HID + lane];
    }
#pragma unroll
    for (int k = 0; k < K_NN; ++k) {
      float h0 = hv0 + v0[k], h1 = hv1 + v1[k];
      s1 += h0 + h1;
      s2 = fmaf(h0, h0, s2); s2 = fmaf(h1, h1, s2);
    }
  }

  __shared__ float red[4][HID];
  red[wv][lane] = s1;
  __syncthreads();
  if (threadIdx.x < HID)
    partial[(size_t)blockIdx.x * 128 + lane] =
        (red[0][lane] + red[1][lane]) + (red[2][lane] + red[3][lane]);
  __syncthreads();
  red[wv][lane] = s2;
  __syncthreads();
  if (threadIdx.x < HID)
    partial[(size_t)blockIdx.x * 128 + 64 + lane] =
        (red[0][lane] + red[1][lane]) + (red[2][lane] + red[3][lane]);
}

// ---------------------------------------------------------------------------
__global__ void bn_reduce_finalize_kernel(const float* __restrict__ g,
                                          const float* __restrict__ be,
                                          const float* __restrict__ partial,
                                          float* __restrict__ stats) {
  int t = threadIdx.x;                               // 0..127
  float a0 = 0.f, a1 = 0.f, a2 = 0.f, a3 = 0.f;
  for (int gb = 0; gb < 1024; gb += 4) {
    a0 += partial[(size_t)(gb + 0) * 128 + t];
    a1 += partial[(size_t)(gb + 1) * 128 + t];
    a2 += partial[(size_t)(gb + 2) * 128 + t];
    a3 += partial[(size_t)(gb + 3) * 128 + t];
  }
  __shared__ float sm[128];
  sm[t] = (a0 + a1) + (a2 + a3);
  __syncthreads();
  if (t < HID) {
    const float inv_n = 1.f / (float)(BATCH * NPTS * K_NN);
    float m = sm[t] * inv_n;
    float v = sm[HID + t] * inv_n - m * m;
    float A = g[t] * rsqrtf(v + BN_EPS);
    stats[128 + t] = A;
    stats[192 + t] = be[t] - m * A;
  }
}

// ---------------------------------------------------------------------------
// egapply_gemm: BN-apply + relu + mean-over-K + W2 + b2 + fused d2 of the
// output row + fused bf16 3-way split of the output (feeds next knn).
// ---------------------------------------------------------------------------
__global__ __launch_bounds__(256) void egapply_gemm_kernel(
    const int* __restrict__ idx, const float* __restrict__ hxi,
    const float* __restrict__ hxj, const float* __restrict__ stats,
    const float* __restrict__ W2, const float* __restrict__ b2,
    float* __restrict__ out, float* __restrict__ d2out,
    unsigned short* __restrict__ xsh, unsigned short* __restrict__ xsm,
    unsigned short* __restrict__ xsl) {
  __shared__ float w2s[HID * HID];
  __shared__ float red[32][HID];
  for (int t = threadIdx.x; t < HID * HID; t += 256) w2s[t] = W2[t];

  const int lane = threadIdx.x & 63;
  const int wv   = __builtin_amdgcn_readfirstlane(threadIdx.x >> 6);
  const int node0 = blockIdx.x * 32;
  const float A = stats[128 + lane], Bc = stats[192 + lane];

#pragma unroll 1
  for (int it = 0; it < 4; ++it) {
    const int n0 = node0 + it * 8 + wv;              // uniform
    const int n1 = n0 + 4;
    const int bbase = (n0 >> 10) << 10;
    const int* ip0 = idx + (size_t)n0 * K_NN;        // uniform -> s_load
    const int* ip1 = idx + (size_t)n1 * K_NN;
    int j0[K_NN], j1[K_NN];
#pragma unroll
    for (int k = 0; k < K_NN; ++k) { j0[k] = ip0[k]; j1[k] = ip1[k]; }
    const float hv0 = hxi[(size_t)n0 * HID + lane];
    const float hv1 = hxi[(size_t)n1 * HID + lane];
    float v0[K_NN], v1[K_NN];
#pragma unroll
    for (int k = 0; k < K_NN; ++k) {
      v0[k] = hxj[(size_t)(bbase + j0[k]) * HID + lane];
      v1[k] = hxj[(size_t)(bbase + j1[k]) * HID + lane];
    }
    float a0 = 0.f, a1 = 0.f;
#pragma unroll
    for (int k = 0; k < K_NN; ++k) {
      a0 += fmaxf(fmaf(A, hv0 + v0[k], Bc), 0.f);
      a1 += fmaxf(fmaf(A, hv1 + v1[k], Bc), 0.f);
    }
    red[it * 8 + wv][lane] = a0;
    red[it * 8 + 4 + wv][lane] = a1;
  }
  __syncthreads();

  const float b2f = b2[lane];
  const float inv = 1.f / (float)K_NN;
#pragma unroll 2
  for (int p = 0; p < 8; ++p) {
    int rr = p * 4 + wv;                             // uniform row
    float acc = 0.f;
#pragma unroll 8
    for (int h = 0; h < HID; ++h) acc = fmaf(red[rr][h], w2s[h * HID + lane], acc);
    float val = fmaf(acc, inv, b2f);
    const size_t o = (size_t)(node0 + rr) * HID + lane;
    out[o] = val;

    // bf16 3-way split (RNE, Sterbenz-exact residuals)
    unsigned u = __float_as_uint(val);
    unsigned short hh = (unsigned short)((u + 0x7FFFu + ((u >> 16) & 1u)) >> 16);
    float r1 = val - __uint_as_float((unsigned)hh << 16);
    unsigned ur = __float_as_uint(r1);
    unsigned short mm = (unsigned short)((ur + 0x7FFFu + ((ur >> 16) & 1u)) >> 16);
    float r2 = r1 - __uint_as_float((unsigned)mm << 16);
    unsigned ur2 = __float_as_uint(r2);
    unsigned short ll = (unsigned short)((ur2 + 0x7FFFu + ((ur2 >> 16) & 1u)) >> 16);
    xsh[o] = hh; xsm[o] = mm; xsl[o] = ll;

    float sq = val * val;                            // fused d2 of the row
#pragma unroll
    for (int off = 1; off < 64; off <<= 1) sq += __shfl_xor(sq, off, 64);
    if (lane == 0) d2out[node0 + rr] = sq;
  }
}

// ---------------------------------------------------------------------------
__global__ __launch_bounds__(256) void pool_kernel(const float* __restrict__ h,
                                                   float* __restrict__ pooled) {
  const int b = blockIdx.x;
  const int f = threadIdx.x & 63;
  const int gsz = threadIdx.x >> 6;
  __shared__ float red[4][HID];
  float s = 0.f;
  for (int n = gsz; n < NPTS; n += 4) s += h[((size_t)b * NPTS + n) * HID + f];
  red[gsz][f] = s;
  __syncthreads();
  if (threadIdx.x < HID)
    pooled[b * HID + f] = ((red[0][f] + red[1][f]) + (red[2][f] + red[3][f])) * (1.f / (float)NPTS);
}

__global__ __launch_bounds__(256) void head_kernel(const float* __restrict__ pooled,
    const float* __restrict__ wf1, const float* __restrict__ bf1,
    const float* __restrict__ gf, const float* __restrict__ bef,
    const float* __restrict__ wf2, const float* __restrict__ bf2,
    float* __restrict__ out) {
  __shared__ float pl[BATCH * HID];
  __shared__ float t[BATCH * 32];
  __shared__ float Ab[32], Bb[32];
  for (int i = threadIdx.x; i < BATCH * HID; i += 256) pl[i] = pooled[i];
  __syncthreads();
  for (int i = threadIdx.x; i < BATCH * 32; i += 256) {
    int s = i >> 5, f1 = i & 31;
    float acc = bf1[f1];
    for (int h = 0; h < HID; ++h) acc = fmaf(pl[s * HID + h], wf1[h * 32 + f1], acc);
    t[i] = acc;
  }
  __syncthreads();
  if (threadIdx.x < 32) {
    int f1 = threadIdx.x;
    float m = 0.f;
    for (int s = 0; s < BATCH; ++s) m += t[s * 32 + f1];
    m *= (1.f / (float)BATCH);
    float v = 0.f;
    for (int s = 0; s < BATCH; ++s) { float d = t[s * 32 + f1] - m; v = fmaf(d, d, v); }
    v *= (1.f / (float)BATCH);
    float A = gf[f1] * rsqrtf(v + BN_EPS);
    Ab[f1] = A; Bb[f1] = bef[f1] - m * A;
  }
  __syncthreads();
  for (int i = threadIdx.x; i < BATCH * 32; i += 256) {
    int f1 = i & 31;
    t[i] = fmaxf(fmaf(Ab[f1], t[i], Bb[f1]), 0.f);
  }
  __syncthreads();
  if (threadIdx.x < BATCH * 2) {
    int s = threadIdx.x >> 1, o = threadIdx.x & 1;
    float acc = bf2[o];
    for (int f1 = 0; f1 < 32; ++f1) acc = fmaf(t[s * 32 + f1], wf2[f1 * 2 + o], acc);
    out[s * 2 + o] = acc;
  }
}

// ---------------------------------------------------------------------------
extern "C" void kernel_launch(void* const* d_in, const int* in_sizes, int n_in,
                              void* d_out, int out_size, void* d_ws, size_t ws_size,
                              hipStream_t stream) {
  const float* x   = (const float*)d_in[0];
  const float* w0a = (const float*)d_in[1];
  const float* b0a = (const float*)d_in[2];
  const float* g0  = (const float*)d_in[3];
  const float* be0 = (const float*)d_in[4];
  const float* w0b = (const float*)d_in[5];
  const float* b0b = (const float*)d_in[6];
  const float* wa  = (const float*)d_in[7];
  const float* ba  = (const float*)d_in[8];
  const float* ga  = (const float*)d_in[9];
  const float* bea = (const float*)d_in[10];
  const float* wb  = (const float*)d_in[11];
  const float* bb  = (const float*)d_in[12];
  const float* wf1 = (const float*)d_in[13];
  const float* bf1 = (const float*)d_in[14];
  const float* gf  = (const float*)d_in[15];
  const float* bef = (const float*)d_in[16];
  const float* wf2 = (const float*)d_in[17];
  const float* bf2 = (const float*)d_in[18];

  float* ws = (float*)d_ws;
  const size_t HN = (size_t)BATCH * NPTS * HID;         // 2,097,152
  const size_t ROWS = (size_t)BATCH * NPTS;             // 32768
  float* bufA    = ws;                                  // HN
  float* bufB    = bufA + HN;                           // HN
  float* hxi     = bufB + HN;                           // HN
  float* hxjb    = hxi + HN;                            // HN
  int*   idxb    = (int*)(hxjb + HN);                   // ROWS*12
  float* d2buf   = (float*)(idxb + ROWS * K_NN);        // ROWS
  float* stats   = d2buf + ROWS;                        // 256
  float* partial = stats + 256;                         // 1024*128
  float* pooled  = partial + 1024 * 128;                // 2048
  unsigned short* xsh = (unsigned short*)(pooled + 2048);   // HN bf16
  unsigned short* xsm = xsh + HN;
  unsigned short* xsl = xsm + HN;
  // total ~46 MB of workspace

  // ---- layer 0 (C=3, gather path) ----
  d2_kernel<3><<<(int)(ROWS / 256), 256, 0, stream>>>(x, d2buf);
  knn3_kernel<<<dim3(16, BATCH), 512, 0, stream>>>(x, d2buf, idxb);
  dual3_kernel<<<1024, 256, 0, stream>>>(x, w0a, b0a, hxi, hxjb);
  egstats_kernel<<<1024, 256, 0, stream>>>(idxb, hxi, hxjb, partial);
  bn_reduce_finalize_kernel<<<1, 128, 0, stream>>>(g0, be0, partial, stats);
  egapply_gemm_kernel<<<1024, 256, 0, stream>>>(idxb, hxi, hxjb, stats, w0b, b0b,
                                                bufA, d2buf, xsh, xsm, xsl);

  // ---- layers 1..3 (MFMA knn + gather path) ----
  const float* cur = bufA;
  float* nxt = bufB;
  for (int i = 0; i < 3; ++i) {
    knn64_mfma_kernel<<<dim3(16, BATCH), 512, 0, stream>>>(xsh, xsm, xsl, d2buf, idxb);
    rowgemm2_kernel<<<(int)(ROWS / 32), 256, 0, stream>>>(cur, wa + (size_t)i * 8192,
                                                          ba + i * HID, hxi, hxjb);
    egstats_kernel<<<1024, 256, 0, stream>>>(idxb, hxi, hxjb, partial);
    bn_reduce_finalize_kernel<<<1, 128, 0, stream>>>(ga + i * HID, bea + i * HID, partial, stats);
    egapply_gemm_kernel<<<1024, 256, 0, stream>>>(idxb, hxi, hxjb, stats,
                                                  wb + (size_t)i * 4096, bb + i * HID,
                                                  nxt, d2buf, xsh, xsm, xsl);
    const float* t = cur; cur = nxt; nxt = (float*)t;
  }

  pool_kernel<<<BATCH, 256, 0, stream>>>(cur, pooled);
  head_kernel<<<1, 256, 0, stream>>>(pooled, wf1, bf1, gf, bef, wf2, bf2, (float*)d_out);
}

// Round 18
// 919.655 us; speedup vs baseline: 1.1230x; 1.0041x over previous
//
#include <hip/hip_runtime.h>
#include <cstddef>

#define BATCH 32
#define NPTS  1024
#define K_NN  12
#define HID   64
#define BN_EPS 1e-5f

typedef short bf16x8 __attribute__((ext_vector_type(8)));
typedef float f32x4 __attribute__((ext_vector_type(4)));

// ---------------------------------------------------------------------------
// d2[j] = ||x_j||^2 (layer-0 input only; later layers fused into egapply).
// ---------------------------------------------------------------------------
template<int C>
__global__ __launch_bounds__(256) void d2_kernel(const float* __restrict__ x,
                                                 float* __restrict__ d2) {
  int gid = blockIdx.x * 256 + threadIdx.x;          // < B*N
  const float* xp = x + (size_t)gid * C;
  float s = 0.f;
#pragma unroll
  for (int c = 0; c < C; ++c) { float v = xp[c]; s = fmaf(v, v, s); }
  d2[gid] = s;
}

// ---------------------------------------------------------------------------
// kNN C=64 via MFMA — R15/R17 proven body (142 us) + software-pipelined
// B-fragments: next chunk's 6 B-loads issue before this chunk's scan phase
// (~1000 VALU cycles of shadow). +24 VGPR, bounded at <=128 to preserve
// 2 blocks/CU (R16's reshape exceeded budget and spilled; reverted then).
// Split-bf16 6-product emulation is numerically transparent (absmax
// unchanged since R15). Exact (d,j) lexicographic insert.
// ---------------------------------------------------------------------------
__global__ __launch_bounds__(512, 2) void knn64_mfma_kernel(
    const unsigned short* __restrict__ xh, const unsigned short* __restrict__ xm,
    const unsigned short* __restrict__ xl, const float* __restrict__ d2,
    int* __restrict__ idx) {
  const int b    = blockIdx.y;
  const int lane = threadIdx.x & 63;
  const int wv_u = __builtin_amdgcn_readfirstlane(threadIdx.x >> 6);  // 0..7
  const int i0   = blockIdx.x * 64;
  const size_t bbase = (size_t)b * NPTS;
  const float* d2b = d2 + bbase;

  constexpr int NE = 8 * K_NN;                       // 96
  __shared__ __align__(16) char smem[64 * (NE + 1) * 8];   // 49664 B
  float* slab  = (float*)(smem + wv_u * (64 * 17 * 4));    // 8 x 4352 B
  float* lds_d = (float*)smem;                       // merge arrays (after sync)
  int*   lds_j = (int*)(smem + 64 * (NE + 1) * 4);

  const int qr = lane >> 4;                          // quad 0..3
  const int lr = lane & 15;

  float bd[K_NN]; int bj[K_NN];
#pragma unroll
  for (int k = 0; k < K_NN; ++k) { bd[k] = 3.4e38f; bj[k] = 0x7fffffff; }

  const int j0 = wv_u * 128;

  // prefetch chunk 0's B frags
  bf16x8 Bh0, Bh1, Bm0, Bm1, Bl0, Bl1;
  {
    const size_t brow = (bbase + j0 + lr) * HID;
    Bh0 = *(const bf16x8*)(xh + brow + 0  + qr * 8);
    Bh1 = *(const bf16x8*)(xh + brow + 32 + qr * 8);
    Bm0 = *(const bf16x8*)(xm + brow + 0  + qr * 8);
    Bm1 = *(const bf16x8*)(xm + brow + 32 + qr * 8);
    Bl0 = *(const bf16x8*)(xl + brow + 0  + qr * 8);
    Bl1 = *(const bf16x8*)(xl + brow + 32 + qr * 8);
  }

#pragma unroll 1
  for (int chunk = 0; chunk < 8; ++chunk) {
    const int jb = j0 + chunk * 16;
    const bf16x8 bh0 = Bh0, bh1 = Bh1, bm0 = Bm0, bm1 = Bm1, bl0 = Bl0, bl1 = Bl1;

    f32x4 acc[4];
#pragma unroll
    for (int isub = 0; isub < 4; ++isub) acc[isub] = f32x4{0.f, 0.f, 0.f, 0.f};

#pragma unroll
    for (int isub = 0; isub < 4; ++isub) {
      const size_t arow = (bbase + i0 + isub * 16 + lr) * HID;
      bf16x8 Ah0 = *(const bf16x8*)(xh + arow + 0  + qr * 8);
      bf16x8 Ah1 = *(const bf16x8*)(xh + arow + 32 + qr * 8);
      bf16x8 Am0 = *(const bf16x8*)(xm + arow + 0  + qr * 8);
      bf16x8 Am1 = *(const bf16x8*)(xm + arow + 32 + qr * 8);
      bf16x8 Al0 = *(const bf16x8*)(xl + arow + 0  + qr * 8);
      bf16x8 Al1 = *(const bf16x8*)(xl + arow + 32 + qr * 8);
      f32x4 a = acc[isub];
      a = __builtin_amdgcn_mfma_f32_16x16x32_bf16(Ah0, bh0, a, 0, 0, 0);
      a = __builtin_amdgcn_mfma_f32_16x16x32_bf16(Ah1, bh1, a, 0, 0, 0);
      a = __builtin_amdgcn_mfma_f32_16x16x32_bf16(Ah0, bm0, a, 0, 0, 0);
      a = __builtin_amdgcn_mfma_f32_16x16x32_bf16(Ah1, bm1, a, 0, 0, 0);
      a = __builtin_amdgcn_mfma_f32_16x16x32_bf16(Am0, bh0, a, 0, 0, 0);
      a = __builtin_amdgcn_mfma_f32_16x16x32_bf16(Am1, bh1, a, 0, 0, 0);
      a = __builtin_amdgcn_mfma_f32_16x16x32_bf16(Ah0, bl0, a, 0, 0, 0);
      a = __builtin_amdgcn_mfma_f32_16x16x32_bf16(Ah1, bl1, a, 0, 0, 0);
      a = __builtin_amdgcn_mfma_f32_16x16x32_bf16(Al0, bh0, a, 0, 0, 0);
      a = __builtin_amdgcn_mfma_f32_16x16x32_bf16(Al1, bh1, a, 0, 0, 0);
      a = __builtin_amdgcn_mfma_f32_16x16x32_bf16(Am0, bm0, a, 0, 0, 0);
      a = __builtin_amdgcn_mfma_f32_16x16x32_bf16(Am1, bm1, a, 0, 0, 0);
      acc[isub] = a;
    }

    if (chunk < 7) {                                 // prefetch next chunk's B
      const size_t nrow = (bbase + jb + 16 + lr) * HID;
      Bh0 = *(const bf16x8*)(xh + nrow + 0  + qr * 8);
      Bh1 = *(const bf16x8*)(xh + nrow + 32 + qr * 8);
      Bm0 = *(const bf16x8*)(xm + nrow + 0  + qr * 8);
      Bm1 = *(const bf16x8*)(xm + nrow + 32 + qr * 8);
      Bl0 = *(const bf16x8*)(xl + nrow + 0  + qr * 8);
      Bl1 = *(const bf16x8*)(xl + nrow + 32 + qr * 8);
    }

    // D -> slab: row = isub*16 + qr*4 + r, col = lr (stride 17)
#pragma unroll
    for (int isub = 0; isub < 4; ++isub)
#pragma unroll
      for (int r = 0; r < 4; ++r)
        slab[(isub * 16 + qr * 4 + r) * 17 + lr] = acc[isub][r];

    // lane = i-row, scan 16 j's ascending (stable order)
#pragma unroll 4
    for (int jj = 0; jj < 16; ++jj) {
      const int j = jb + jj;                         // uniform
      const float dot = slab[lane * 17 + jj];
      // d2_i (row-constant) dropped: doesn't change per-row top-k order.
      const float dval = fmaf(-2.f, dot, d2b[j]);    // uniform s_load
      if (dval < bd[K_NN - 1]) {                     // strict <: lower j wins
        float dk = dval; int jk = j;
#pragma unroll
        for (int s = 0; s < K_NN; ++s) {             // exact branchless insert
          bool sw = dk < bd[s];
          float nd = fminf(dk, bd[s]);
          float xd = fmaxf(dk, bd[s]);
          int nj = sw ? jk : bj[s];
          int xjj = sw ? bj[s] : jk;
          bd[s] = nd; bj[s] = nj; dk = xd; jk = xjj;
        }
      }
    }
  }

  __syncthreads();                                   // slabs dead -> merge arrays
#pragma unroll
  for (int k = 0; k < K_NN; ++k) {
    lds_d[lane * (NE + 1) + wv_u * K_NN + k] = bd[k];
    lds_j[lane * (NE + 1) + wv_u * K_NN + k] = bj[k];
  }
  __syncthreads();

  if (wv_u == 0) {                                   // merge 8 sorted slices
    float md[K_NN]; int mj[K_NN];
#pragma unroll
    for (int k = 0; k < K_NN; ++k) { md[k] = 3.4e38f; mj[k] = 0x7fffffff; }
    for (int e = 0; e < NE; ++e) {                   // ascending slice order
      float dk = lds_d[lane * (NE + 1) + e];
      int jk = lds_j[lane * (NE + 1) + e];
      if (dk < md[K_NN - 1]) {
#pragma unroll
        for (int s = 0; s < K_NN; ++s) {
          bool sw = dk < md[s];
          float nd = fminf(dk, md[s]);
          float xd = fmaxf(dk, md[s]);
          int nj = sw ? jk : mj[s];
          int xjj = sw ? mj[s] : jk;
          md[s] = nd; mj[s] = nj; dk = xd; jk = xjj;
        }
      }
    }
    int* op = idx + ((size_t)b * NPTS + i0 + lane) * K_NN;
#pragma unroll
    for (int k = 0; k < K_NN; ++k) op[k] = mj[k];
  }
}

// ---------------------------------------------------------------------------
// kNN C=3 (layer 0): xi[3] in registers, scalar v_fma with SGPR xj.
// ---------------------------------------------------------------------------
__global__ __launch_bounds__(512, 2) void knn3_kernel(
    const float* __restrict__ x, const float* __restrict__ d2,
    int* __restrict__ idx) {
  const int b    = blockIdx.y;
  const int lane = threadIdx.x & 63;
  const int wv_u = __builtin_amdgcn_readfirstlane(threadIdx.x >> 6);  // 0..7
  const int i    = blockIdx.x * 64 + lane;
  const float* xb  = x  + (size_t)b * NPTS * 3;
  const float* d2b = d2 + (size_t)b * NPTS;

  constexpr int NE = 8 * K_NN;
  __shared__ float lds_d[64][NE + 1];
  __shared__ int   lds_j[64][NE + 1];

  float xi0 = xb[(size_t)i * 3 + 0];
  float xi1 = xb[(size_t)i * 3 + 1];
  float xi2v = xb[(size_t)i * 3 + 2];

  float bd[K_NN]; int bj[K_NN];
#pragma unroll
  for (int k = 0; k < K_NN; ++k) { bd[k] = 3.4e38f; bj[k] = 0x7fffffff; }

  const int j0 = wv_u * 128;
#pragma unroll 2
  for (int jj = 0; jj < 128; ++jj) {
    const int j = j0 + jj;                           // uniform
    const float* xj = xb + (size_t)j * 3;            // uniform -> s_load
    const float d2j = d2b[j];
    float dot = fmaf(xi0, xj[0], 0.f);
    dot = fmaf(xi1, xj[1], dot);
    dot = fmaf(xi2v, xj[2], dot);
    const float dval = fmaf(-2.f, dot, d2j);
    if (dval < bd[K_NN - 1]) {
      float dk = dval; int jk = j;
#pragma unroll
      for (int s = 0; s < K_NN; ++s) {
        bool sw = dk < bd[s];
        float nd = fminf(dk, bd[s]);
        float xd = fmaxf(dk, bd[s]);
        int nj = sw ? jk : bj[s];
        int xjj = sw ? bj[s] : jk;
        bd[s] = nd; bj[s] = nj; dk = xd; jk = xjj;
      }
    }
  }

#pragma unroll
  for (int k = 0; k < K_NN; ++k) {
    lds_d[lane][wv_u * K_NN + k] = bd[k];
    lds_j[lane][wv_u * K_NN + k] = bj[k];
  }
  __syncthreads();

  if (wv_u == 0) {
    float md[K_NN]; int mj[K_NN];
#pragma unroll
    for (int k = 0; k < K_NN; ++k) { md[k] = 3.4e38f; mj[k] = 0x7fffffff; }
    for (int e = 0; e < NE; ++e) {
      float dk = lds_d[lane][e]; int jk = lds_j[lane][e];
      if (dk < md[K_NN - 1]) {
#pragma unroll
        for (int s = 0; s < K_NN; ++s) {
          bool sw = dk < md[s];
          float nd = fminf(dk, md[s]);
          float xd = fmaxf(dk, md[s]);
          int nj = sw ? jk : mj[s];
          int xjj = sw ? mj[s] : jk;
          md[s] = nd; mj[s] = nj; dk = xd; jk = xjj;
        }
      }
    }
    int* op = idx + ((size_t)b * NPTS + blockIdx.x * 64 + lane) * K_NN;
#pragma unroll
    for (int k = 0; k < K_NN; ++k) op[k] = mj[k];
  }
}

// ---------------------------------------------------------------------------
// rowgemm2: dual-output 64x64 rowgemm, W1a-W1b folded into LDS staging.
// ---------------------------------------------------------------------------
__global__ __launch_bounds__(256) void rowgemm2_kernel(
    const float* __restrict__ X, const float* __restrict__ waL,
    const float* __restrict__ biasA,
    float* __restrict__ YA, float* __restrict__ YB) {
  __shared__ float wsa[HID * HID];
  __shared__ float wsb[HID * HID];
  for (int t = threadIdx.x; t < HID * HID; t += 256) {
    float wbv = waL[4096 + t];
    wsa[t] = waL[t] - wbv;
    wsb[t] = wbv;
  }
  __syncthreads();

  const int lane = threadIdx.x & 63;
  const int wv   = threadIdx.x >> 6;
  const int fq   = lane & 15;
  const int rg   = lane >> 4;
  const int r0   = blockIdx.x * 32 + wv * 8 + rg * 2;

  const float4* X4 = (const float4*)X;
  const float4* WA4 = (const float4*)wsa;
  const float4* WB4 = (const float4*)wsb;
  float aA0[4] = {0,0,0,0}, aA1[4] = {0,0,0,0};
  float aB0[4] = {0,0,0,0}, aB1[4] = {0,0,0,0};

#pragma unroll 2
  for (int cq = 0; cq < 16; ++cq) {
    float4 xa = X4[(size_t)r0 * 16 + cq];
    float4 xb_ = X4[(size_t)(r0 + 1) * 16 + cq];
    float ea[4] = {xa.x, xa.y, xa.z, xa.w};
    float eb[4] = {xb_.x, xb_.y, xb_.z, xb_.w};
#pragma unroll
    for (int d = 0; d < 4; ++d) {
      float4 wa4 = WA4[(cq * 4 + d) * 16 + fq];
      float4 wb4 = WB4[(cq * 4 + d) * 16 + fq];
      float wA[4] = {wa4.x, wa4.y, wa4.z, wa4.w};
      float wB[4] = {wb4.x, wb4.y, wb4.z, wb4.w};
#pragma unroll
      for (int k = 0; k < 4; ++k) {
        aA0[k] = fmaf(ea[d], wA[k], aA0[k]);
        aA1[k] = fmaf(eb[d], wA[k], aA1[k]);
        aB0[k] = fmaf(ea[d], wB[k], aB0[k]);
        aB1[k] = fmaf(eb[d], wB[k], aB1[k]);
      }
    }
  }
  float4 b4 = ((const float4*)biasA)[fq];
  float4 oA0{aA0[0] + b4.x, aA0[1] + b4.y, aA0[2] + b4.z, aA0[3] + b4.w};
  float4 oA1{aA1[0] + b4.x, aA1[1] + b4.y, aA1[2] + b4.z, aA1[3] + b4.w};
  float4 oB0{aB0[0], aB0[1], aB0[2], aB0[3]};
  float4 oB1{aB1[0], aB1[1], aB1[2], aB1[3]};
  ((float4*)YA)[(size_t)r0 * 16 + fq] = oA0;
  ((float4*)YA)[(size_t)(r0 + 1) * 16 + fq] = oA1;
  ((float4*)YB)[(size_t)r0 * 16 + fq] = oB0;
  ((float4*)YB)[(size_t)(r0 + 1) * 16 + fq] = oB1;
}

// ---------------------------------------------------------------------------
// dual3: layer-0 projections (C=3), subtraction folded into staging.
// ---------------------------------------------------------------------------
__global__ __launch_bounds__(256) void dual3_kernel(
    const float* __restrict__ x, const float* __restrict__ w0a,
    const float* __restrict__ b1,
    float* __restrict__ hxi, float* __restrict__ hxj) {
  __shared__ float Cs[3 * HID], Bs[3 * HID], bs[HID];
  for (int t = threadIdx.x; t < 3 * HID; t += 256) {
    float bv = w0a[192 + t];
    Cs[t] = w0a[t] - bv;
    Bs[t] = bv;
  }
  if (threadIdx.x < HID) bs[threadIdx.x] = b1[threadIdx.x];
  __syncthreads();

  const int lane = threadIdx.x & 63;
  const int wv   = __builtin_amdgcn_readfirstlane(threadIdx.x >> 6);
  const int node0 = blockIdx.x * 32;
#pragma unroll 1
  for (int it = 0; it < 8; ++it) {
    const int n = node0 + it * 4 + wv;               // uniform
    const float* xr = x + (size_t)n * 3;             // uniform -> s_load
    float x0 = xr[0], x1 = xr[1], x2 = xr[2];
    float hi = bs[lane];
    hi = fmaf(x0, Cs[0 * HID + lane], hi);
    hi = fmaf(x1, Cs[1 * HID + lane], hi);
    hi = fmaf(x2, Cs[2 * HID + lane], hi);
    float hj = x0 * Bs[0 * HID + lane];
    hj = fmaf(x1, Bs[1 * HID + lane], hj);
    hj = fmaf(x2, Bs[2 * HID + lane], hj);
    hxi[(size_t)n * HID + lane] = hi;
    hxj[(size_t)n * HID + lane] = hj;
  }
}

// ---------------------------------------------------------------------------
// egstats: BN sum/sumsq over all edges of h = hxi[n] + hxj[j].
// ---------------------------------------------------------------------------
__global__ __launch_bounds__(256) void egstats_kernel(
    const int* __restrict__ idx, const float* __restrict__ hxi,
    const float* __restrict__ hxj, float* __restrict__ partial) {
  const int lane = threadIdx.x & 63;
  const int wv   = __builtin_amdgcn_readfirstlane(threadIdx.x >> 6);
  const int node0 = blockIdx.x * 32;
  float s1 = 0.f, s2 = 0.f;

#pragma unroll 1
  for (int it = 0; it < 4; ++it) {
    const int n0 = node0 + it * 8 + wv;              // uniform
    const int n1 = n0 + 4;
    const int bbase = (n0 >> 10) << 10;
    const int* ip0 = idx + (size_t)n0 * K_NN;        // uniform -> s_load
    const int* ip1 = idx + (size_t)n1 * K_NN;
    int j0[K_NN], j1[K_NN];
#pragma unroll
    for (int k = 0; k < K_NN; ++k) { j0[k] = ip0[k]; j1[k] = ip1[k]; }
    const float hv0 = hxi[(size_t)n0 * HID + lane];
    const float hv1 = hxi[(size_t)n1 * HID + lane];
    float v0[K_NN], v1[K_NN];
#pragma unroll
    for (int k = 0; k < K_NN; ++k) {
      v0[k] = hxj[(size_t)(bbase + j0[k]) * HID + lane];
      v1[k] = hxj[(size_t)(bbase + j1[k]) * HID + lane];
    }
#pragma unroll
    for (int k = 0; k < K_NN; ++k) {
      float h0 = hv0 + v0[k], h1 = hv1 + v1[k];
      s1 += h0 + h1;
      s2 = fmaf(h0, h0, s2); s2 = fmaf(h1, h1, s2);
    }
  }

  __shared__ float red[4][HID];
  red[wv][lane] = s1;
  __syncthreads();
  if (threadIdx.x < HID)
    partial[(size_t)blockIdx.x * 128 + lane] =
        (red[0][lane] + red[1][lane]) + (red[2][lane] + red[3][lane]);
  __syncthreads();
  red[wv][lane] = s2;
  __syncthreads();
  if (threadIdx.x < HID)
    partial[(size_t)blockIdx.x * 128 + 64 + lane] =
        (red[0][lane] + red[1][lane]) + (red[2][lane] + red[3][lane]);
}

// ---------------------------------------------------------------------------
__global__ void bn_reduce_finalize_kernel(const float* __restrict__ g,
                                          const float* __restrict__ be,
                                          const float* __restrict__ partial,
                                          float* __restrict__ stats) {
  int t = threadIdx.x;                               // 0..127
  float a0 = 0.f, a1 = 0.f, a2 = 0.f, a3 = 0.f;
  for (int gb = 0; gb < 1024; gb += 4) {
    a0 += partial[(size_t)(gb + 0) * 128 + t];
    a1 += partial[(size_t)(gb + 1) * 128 + t];
    a2 += partial[(size_t)(gb + 2) * 128 + t];
    a3 += partial[(size_t)(gb + 3) * 128 + t];
  }
  __shared__ float sm[128];
  sm[t] = (a0 + a1) + (a2 + a3);
  __syncthreads();
  if (t < HID) {
    const float inv_n = 1.f / (float)(BATCH * NPTS * K_NN);
    float m = sm[t] * inv_n;
    float v = sm[HID + t] * inv_n - m * m;
    float A = g[t] * rsqrtf(v + BN_EPS);
    stats[128 + t] = A;
    stats[192 + t] = be[t] - m * A;
  }
}

// ---------------------------------------------------------------------------
// egapply_gemm: BN-apply + relu + mean-over-K + W2 + b2 + fused d2 of the
// output row + fused bf16 3-way split of the output (feeds next knn).
// ---------------------------------------------------------------------------
__global__ __launch_bounds__(256) void egapply_gemm_kernel(
    const int* __restrict__ idx, const float* __restrict__ hxi,
    const float* __restrict__ hxj, const float* __restrict__ stats,
    const float* __restrict__ W2, const float* __restrict__ b2,
    float* __restrict__ out, float* __restrict__ d2out,
    unsigned short* __restrict__ xsh, unsigned short* __restrict__ xsm,
    unsigned short* __restrict__ xsl) {
  __shared__ float w2s[HID * HID];
  __shared__ float red[32][HID];
  for (int t = threadIdx.x; t < HID * HID; t += 256) w2s[t] = W2[t];

  const int lane = threadIdx.x & 63;
  const int wv   = __builtin_amdgcn_readfirstlane(threadIdx.x >> 6);
  const int node0 = blockIdx.x * 32;
  const float A = stats[128 + lane], Bc = stats[192 + lane];

#pragma unroll 1
  for (int it = 0; it < 4; ++it) {
    const int n0 = node0 + it * 8 + wv;              // uniform
    const int n1 = n0 + 4;
    const int bbase = (n0 >> 10) << 10;
    const int* ip0 = idx + (size_t)n0 * K_NN;        // uniform -> s_load
    const int* ip1 = idx + (size_t)n1 * K_NN;
    int j0[K_NN], j1[K_NN];
#pragma unroll
    for (int k = 0; k < K_NN; ++k) { j0[k] = ip0[k]; j1[k] = ip1[k]; }
    const float hv0 = hxi[(size_t)n0 * HID + lane];
    const float hv1 = hxi[(size_t)n1 * HID + lane];
    float v0[K_NN], v1[K_NN];
#pragma unroll
    for (int k = 0; k < K_NN; ++k) {
      v0[k] = hxj[(size_t)(bbase + j0[k]) * HID + lane];
      v1[k] = hxj[(size_t)(bbase + j1[k]) * HID + lane];
    }
    float a0 = 0.f, a1 = 0.f;
#pragma unroll
    for (int k = 0; k < K_NN; ++k) {
      a0 += fmaxf(fmaf(A, hv0 + v0[k], Bc), 0.f);
      a1 += fmaxf(fmaf(A, hv1 + v1[k], Bc), 0.f);
    }
    red[it * 8 + wv][lane] = a0;
    red[it * 8 + 4 + wv][lane] = a1;
  }
  __syncthreads();

  const float b2f = b2[lane];
  const float inv = 1.f / (float)K_NN;
#pragma unroll 2
  for (int p = 0; p < 8; ++p) {
    int rr = p * 4 + wv;                             // uniform row
    float acc = 0.f;
#pragma unroll 8
    for (int h = 0; h < HID; ++h) acc = fmaf(red[rr][h], w2s[h * HID + lane], acc);
    float val = fmaf(acc, inv, b2f);
    const size_t o = (size_t)(node0 + rr) * HID + lane;
    out[o] = val;

    // bf16 3-way split (RNE, Sterbenz-exact residuals)
    unsigned u = __float_as_uint(val);
    unsigned short hh = (unsigned short)((u + 0x7FFFu + ((u >> 16) & 1u)) >> 16);
    float r1 = val - __uint_as_float((unsigned)hh << 16);
    unsigned ur = __float_as_uint(r1);
    unsigned short mm = (unsigned short)((ur + 0x7FFFu + ((ur >> 16) & 1u)) >> 16);
    float r2 = r1 - __uint_as_float((unsigned)mm << 16);
    unsigned ur2 = __float_as_uint(r2);
    unsigned short ll = (unsigned short)((ur2 + 0x7FFFu + ((ur2 >> 16) & 1u)) >> 16);
    xsh[o] = hh; xsm[o] = mm; xsl[o] = ll;

    float sq = val * val;                            // fused d2 of the row
#pragma unroll
    for (int off = 1; off < 64; off <<= 1) sq += __shfl_xor(sq, off, 64);
    if (lane == 0) d2out[node0 + rr] = sq;
  }
}

// ---------------------------------------------------------------------------
__global__ __launch_bounds__(256) void pool_kernel(const float* __restrict__ h,
                                                   float* __restrict__ pooled) {
  const int b = blockIdx.x;
  const int f = threadIdx.x & 63;
  const int gsz = threadIdx.x >> 6;
  __shared__ float red[4][HID];
  float s = 0.f;
  for (int n = gsz; n < NPTS; n += 4) s += h[((size_t)b * NPTS + n) * HID + f];
  red[gsz][f] = s;
  __syncthreads();
  if (threadIdx.x < HID)
    pooled[b * HID + f] = ((red[0][f] + red[1][f]) + (red[2][f] + red[3][f])) * (1.f / (float)NPTS);
}

__global__ __launch_bounds__(256) void head_kernel(const float* __restrict__ pooled,
    const float* __restrict__ wf1, const float* __restrict__ bf1,
    const float* __restrict__ gf, const float* __restrict__ bef,
    const float* __restrict__ wf2, const float* __restrict__ bf2,
    float* __restrict__ out) {
  __shared__ float pl[BATCH * HID];
  __shared__ float t[BATCH * 32];
  __shared__ float Ab[32], Bb[32];
  for (int i = threadIdx.x; i < BATCH * HID; i += 256) pl[i] = pooled[i];
  __syncthreads();
  for (int i = threadIdx.x; i < BATCH * 32; i += 256) {
    int s = i >> 5, f1 = i & 31;
    float acc = bf1[f1];
    for (int h = 0; h < HID; ++h) acc = fmaf(pl[s * HID + h], wf1[h * 32 + f1], acc);
    t[i] = acc;
  }
  __syncthreads();
  if (threadIdx.x < 32) {
    int f1 = threadIdx.x;
    float m = 0.f;
    for (int s = 0; s < BATCH; ++s) m += t[s * 32 + f1];
    m *= (1.f / (float)BATCH);
    float v = 0.f;
    for (int s = 0; s < BATCH; ++s) { float d = t[s * 32 + f1] - m; v = fmaf(d, d, v); }
    v *= (1.f / (float)BATCH);
    float A = gf[f1] * rsqrtf(v + BN_EPS);
    Ab[f1] = A; Bb[f1] = bef[f1] - m * A;
  }
  __syncthreads();
  for (int i = threadIdx.x; i < BATCH * 32; i += 256) {
    int f1 = i & 31;
    t[i] = fmaxf(fmaf(Ab[f1], t[i], Bb[f1]), 0.f);
  }
  __syncthreads();
  if (threadIdx.x < BATCH * 2) {
    int s = threadIdx.x >> 1, o = threadIdx.x & 1;
    float acc = bf2[o];
    for (int f1 = 0; f1 < 32; ++f1) acc = fmaf(t[s * 32 + f1], wf2[f1 * 2 + o], acc);
    out[s * 2 + o] = acc;
  }
}

// ---------------------------------------------------------------------------
extern "C" void kernel_launch(void* const* d_in, const int* in_sizes, int n_in,
                              void* d_out, int out_size, void* d_ws, size_t ws_size,
                              hipStream_t stream) {
  const float* x   = (const float*)d_in[0];
  const float* w0a = (const float*)d_in[1];
  const float* b0a = (const float*)d_in[2];
  const float* g0  = (const float*)d_in[3];
  const float* be0 = (const float*)d_in[4];
  const float* w0b = (const float*)d_in[5];
  const float* b0b = (const float*)d_in[6];
  const float* wa  = (const float*)d_in[7];
  const float* ba  = (const float*)d_in[8];
  const float* ga  = (const float*)d_in[9];
  const float* bea = (const float*)d_in[10];
  const float* wb  = (const float*)d_in[11];
  const float* bb  = (const float*)d_in[12];
  const float* wf1 = (const float*)d_in[13];
  const float* bf1 = (const float*)d_in[14];
  const float* gf  = (const float*)d_in[15];
  const float* bef = (const float*)d_in[16];
  const float* wf2 = (const float*)d_in[17];
  const float* bf2 = (const float*)d_in[18];

  float* ws = (float*)d_ws;
  const size_t HN = (size_t)BATCH * NPTS * HID;         // 2,097,152
  const size_t ROWS = (size_t)BATCH * NPTS;             // 32768
  float* bufA    = ws;                                  // HN
  float* bufB    = bufA + HN;                           // HN
  float* hxi     = bufB + HN;                           // HN
  float* hxjb    = hxi + HN;                            // HN
  int*   idxb    = (int*)(hxjb + HN);                   // ROWS*12
  float* d2buf   = (float*)(idxb + ROWS * K_NN);        // ROWS
  float* stats   = d2buf + ROWS;                        // 256
  float* partial = stats + 256;                         // 1024*128
  float* pooled  = partial + 1024 * 128;                // 2048
  unsigned short* xsh = (unsigned short*)(pooled + 2048);   // HN bf16
  unsigned short* xsm = xsh + HN;
  unsigned short* xsl = xsm + HN;
  // total ~46 MB of workspace

  // ---- layer 0 (C=3, gather path) ----
  d2_kernel<3><<<(int)(ROWS / 256), 256, 0, stream>>>(x, d2buf);
  knn3_kernel<<<dim3(16, BATCH), 512, 0, stream>>>(x, d2buf, idxb);
  dual3_kernel<<<1024, 256, 0, stream>>>(x, w0a, b0a, hxi, hxjb);
  egstats_kernel<<<1024, 256, 0, stream>>>(idxb, hxi, hxjb, partial);
  bn_reduce_finalize_kernel<<<1, 128, 0, stream>>>(g0, be0, partial, stats);
  egapply_gemm_kernel<<<1024, 256, 0, stream>>>(idxb, hxi, hxjb, stats, w0b, b0b,
                                                bufA, d2buf, xsh, xsm, xsl);

  // ---- layers 1..3 (MFMA knn + gather path) ----
  const float* cur = bufA;
  float* nxt = bufB;
  for (int i = 0; i < 3; ++i) {
    knn64_mfma_kernel<<<dim3(16, BATCH), 512, 0, stream>>>(xsh, xsm, xsl, d2buf, idxb);
    rowgemm2_kernel<<<(int)(ROWS / 32), 256, 0, stream>>>(cur, wa + (size_t)i * 8192,
                                                          ba + i * HID, hxi, hxjb);
    egstats_kernel<<<1024, 256, 0, stream>>>(idxb, hxi, hxjb, partial);
    bn_reduce_finalize_kernel<<<1, 128, 0, stream>>>(ga + i * HID, bea + i * HID, partial, stats);
    egapply_gemm_kernel<<<1024, 256, 0, stream>>>(idxb, hxi, hxjb, stats,
                                                  wb + (size_t)i * 4096, bb + i * HID,
                                                  nxt, d2buf, xsh, xsm, xsl);
    const float* t = cur; cur = nxt; nxt = (float*)t;
  }

  pool_kernel<<<BATCH, 256, 0, stream>>>(cur, pooled);
  head_kernel<<<1, 256, 0, stream>>>(pooled, wf1, bf1, gf, bef, wf2, bf2, (float*)d_out);
}